// Round 1
// baseline (229.824 us; speedup 1.0000x reference)
//
#include <hip/hip_runtime.h>
#include <cmath>

// Problem constants (from the reference)
//   SRF=3.0, SRF2=9.0, ALPHA=2.0, BETA=8.0, GAMMA=16.0, RES=0.5
//   N_BUCKETS=17, MUL=[289,17,1], SLICES_PER_ROT=2
// Outputs concatenated flat (all written as float32):
//   [0)           N*N*3 : dxyz_m
//   [N*N*3)       N*N   : buckets (int -> float)
//   [N*N*4)       N*N   : dscanid (int -> float)
//   [N*N*5)       N*N   : mask (0/1)

__device__ __forceinline__ float bucket_base(float v) {
    // x = v / RES  (RES=0.5 -> exact *2)
    const float x  = v * 2.0f;
    const float xa = fabsf(x);
    // round path (|x| <= 2): round-half-to-even like jnp.round
    const float rnd = rintf(x);
    // log path
    const float inv_den = (float)2.0794415416798357; // log(GAMMA/ALPHA)=log(8) as f32
    const float lr  = logf(fmaxf(xa, 1e-6f) * 0.5f) / inv_den; // f32 division, matches jax weak-type
    float sup = fminf(rintf(2.0f - 6.0f * lr), 8.0f);
    const float s = (x > 0.0f) ? 1.0f : ((x < 0.0f) ? -1.0f : 0.0f);
    sup = s * sup;
    return 8.0f + ((xa <= 2.0f) ? rnd : sup);
}

__global__ __launch_bounds__(256) void pair_kernel(
    const float* __restrict__ xyz, const int* __restrict__ grid,
    float* __restrict__ out, int N) {
#pragma clang fp contract(off)
    const int j = blockIdx.x * blockDim.x + threadIdx.x;
    const int i = blockIdx.y;
    if (j >= N) return;

    // i-side data: uniform across the block -> scalar loads
    const float xi = xyz[3 * i + 0];
    const float yi = xyz[3 * i + 1];
    const float zi = xyz[3 * i + 2];
    const int   bat_i = grid[5 * i + 0];
    const int   blk_i = grid[5 * i + 1];
    const int   c0i   = grid[5 * i + 2];
    const int   c1i   = grid[5 * i + 3];
    const int   c2i   = grid[5 * i + 4];

    // j-side data: coalesced-ish vector loads (L1/L2 hot after first row)
    const float xj = xyz[3 * j + 0];
    const float yj = xyz[3 * j + 1];
    const float zj = xyz[3 * j + 2];
    const int   bat_j = grid[5 * j + 0];
    const int   blk_j = grid[5 * j + 1];
    const int   c0j   = grid[5 * j + 2];
    const int   c1j   = grid[5 * j + 3];
    const int   c2j   = grid[5 * j + 4];

    const bool batch_eq = (bat_i == bat_j);
    const bool block_le = (blk_i <= blk_j);
    const int  cadj = max(max(abs(c0i - c0j), abs(c1i - c1j)), abs(c2i - c2j));
    const bool forcekeep = (cadj <= 1) && (blk_i == blk_j);

    const int xci = (int)ceilf(xi / 3.0f);
    const int yci = (int)ceilf(yi / 3.0f);
    const int xcj = (int)ceilf(xj / 3.0f);
    const int ycj = (int)ceilf(yj / 3.0f);
    const bool keep_coarse = max(abs(xci - xcj), abs(yci - ycj)) <= 1;

    const float dx = xi - xj;
    const float dy = yi - yj;
    const float dz = zi - zj;
    const float d2 = dx * dx + dy * dy + dz * dz; // contract(off): matches ref f32 ops
    const bool keepr = (d2 <= 9.0f);

    const bool mask = batch_eq && block_le &&
                      (forcekeep || keep_coarse) && (forcekeep || keepr);

    const float dxm = mask ? dx : 0.0f;
    const float dym = mask ? dy : 0.0f;
    const float dzm = mask ? dz : 0.0f;

    const float b0 = bucket_base(dxm);
    const float b1 = bucket_base(dym);
    const float b2 = bucket_base(dzm);
    const float bsum = (289.0f * b0 + 17.0f * b1) + b2; // exact small ints in f32
    const int bucket = mask ? (int)bsum : 0;

    const int dscan = mask ? ((blk_j >> 1) - (blk_i >> 1)) : 0; // block // 2, nonneg

    const size_t NN   = (size_t)N * (size_t)N;
    const size_t base = (size_t)i * (size_t)N + (size_t)j;

    const size_t o0 = base * 3;
    out[o0 + 0] = dxm;
    out[o0 + 1] = dym;
    out[o0 + 2] = dzm;
    out[NN * 3 + base] = (float)bucket;
    out[NN * 4 + base] = (float)dscan;
    out[NN * 5 + base] = mask ? 1.0f : 0.0f;
}

extern "C" void kernel_launch(void* const* d_in, const int* in_sizes, int n_in,
                              void* d_out, int out_size, void* d_ws, size_t ws_size,
                              hipStream_t stream) {
    const float* xyz  = (const float*)d_in[0];
    const int*   grid = (const int*)d_in[1];
    float*       out  = (float*)d_out;
    const int N = in_sizes[0] / 3; // xyz is (N,3)

    const int BLOCK = 256;
    dim3 gdim((N + BLOCK - 1) / BLOCK, N, 1);
    pair_kernel<<<gdim, dim3(BLOCK, 1, 1), 0, stream>>>(xyz, grid, out, N);
}

// Round 2
// 219.641 us; speedup vs baseline: 1.0464x; 1.0464x over previous
//
#include <hip/hip_runtime.h>
#include <cmath>

// Outputs concatenated flat (all float32):
//   [0)      N*N*3 : dxyz_m
//   [N*N*3)  N*N   : buckets
//   [N*N*4)  N*N   : dscanid
//   [N*N*5)  N*N   : mask

__device__ __forceinline__ float bucket_base(float v) {
    // x = v / RES (RES=0.5 -> exact *2)
    const float x  = v * 2.0f;
    const float xa = fabsf(x);
    if (xa <= 2.0f) {
        // round-half-to-even like jnp.round
        return 8.0f + rintf(x);
    }
    // log path only when needed (xa>2 => x != 0)
    const float lr = logf(fmaxf(xa, 1e-6f) * 0.5f) / 2.0794415416798357f; // /log(8)
    const float sup = fminf(rintf(2.0f - 6.0f * lr), 8.0f);
    return 8.0f + ((x > 0.0f) ? sup : -sup);
}

__global__ __launch_bounds__(256) void pair_kernel(
    const float* __restrict__ xyz, const int* __restrict__ grid,
    float* __restrict__ out, int N) {
#pragma clang fp contract(off)
    const int jq = blockIdx.x * blockDim.x + threadIdx.x; // quad-of-j index
    const int j0 = jq << 2;
    const int i  = blockIdx.y;
    if (j0 >= N) return;

    // i-side (wave-uniform -> scalar)
    const float xi = xyz[3 * i + 0];
    const float yi = xyz[3 * i + 1];
    const float zi = xyz[3 * i + 2];
    const int bat_i = grid[5 * i + 0];
    const int blk_i = grid[5 * i + 1];
    const int c0i = grid[5 * i + 2];
    const int c1i = grid[5 * i + 3];
    const int c2i = grid[5 * i + 4];
    const int xci = (int)ceilf(xi / 3.0f);
    const int yci = (int)ceilf(yi / 3.0f);
    const int scan_i = blk_i >> 1;

    // j-side: vectorized loads (j0 % 4 == 0 -> 16B aligned)
    const float4* pv = reinterpret_cast<const float4*>(xyz + (size_t)3 * j0);
    const float4 p0 = pv[0], p1 = pv[1], p2 = pv[2];
    const int4* gv = reinterpret_cast<const int4*>(grid + (size_t)5 * j0);
    const int4 g0 = gv[0], g1 = gv[1], g2 = gv[2], g3 = gv[3], g4 = gv[4];

    const float jx[4]  = {p0.x, p0.w, p1.z, p2.y};
    const float jy[4]  = {p0.y, p1.x, p1.w, p2.z};
    const float jz[4]  = {p0.z, p1.y, p2.x, p2.w};
    const int   jbat[4] = {g0.x, g1.y, g2.z, g3.w};
    const int   jblk[4] = {g0.y, g1.z, g2.w, g4.x};
    const int   jc0[4]  = {g0.z, g1.w, g3.x, g4.y};
    const int   jc1[4]  = {g0.w, g2.x, g3.y, g4.z};
    const int   jc2[4]  = {g1.x, g2.y, g3.z, g4.w};

    float dxm[4], dym[4], dzm[4];
    bool  mk[4];
    bool  any = false;
#pragma unroll
    for (int k = 0; k < 4; ++k) {
        const float dx = xi - jx[k];
        const float dy = yi - jy[k];
        const float dz = zi - jz[k];
        const bool batch_eq = (bat_i == jbat[k]);
        const bool block_le = (blk_i <= jblk[k]);
        const int  cadj = max(max(abs(c0i - jc0[k]), abs(c1i - jc1[k])),
                              abs(c2i - jc2[k]));
        const bool forcekeep = (cadj <= 1) && (blk_i == jblk[k]);
        const int xcj = (int)ceilf(jx[k] / 3.0f);
        const int ycj = (int)ceilf(jy[k] / 3.0f);
        const bool keep_coarse = max(abs(xci - xcj), abs(yci - ycj)) <= 1;
        const float d2 = dx * dx + dy * dy + dz * dz; // contract(off): matches ref
        const bool keepr = (d2 <= 9.0f);
        const bool m = batch_eq && block_le &&
                       (forcekeep || keep_coarse) && (forcekeep || keepr);
        mk[k] = m;
        any |= m;
        dxm[k] = m ? dx : 0.0f;
        dym[k] = m ? dy : 0.0f;
        dzm[k] = m ? dz : 0.0f;
    }

    const size_t NN   = (size_t)N * (size_t)N;
    const size_t base = (size_t)i * (size_t)N + (size_t)j0;
    float4* o_dxyz = reinterpret_cast<float4*>(out + 3 * base);
    float4* o_bkt  = reinterpret_cast<float4*>(out + NN * 3 + base);
    float4* o_dsc  = reinterpret_cast<float4*>(out + NN * 4 + base);
    float4* o_msk  = reinterpret_cast<float4*>(out + NN * 5 + base);

    // Wave-uniform fast path: nothing kept anywhere in this wave -> pure zeros.
    if (__ballot(any ? 1 : 0) == 0ULL) {
        const float4 z = make_float4(0.0f, 0.0f, 0.0f, 0.0f);
        o_dxyz[0] = z; o_dxyz[1] = z; o_dxyz[2] = z;
        o_bkt[0]  = z; o_dsc[0]  = z; o_msk[0]  = z;
        return;
    }

    float bf[4], df[4], mf[4];
#pragma unroll
    for (int k = 0; k < 4; ++k) {
        if (mk[k]) {
            const float b0 = bucket_base(dxm[k]);
            const float b1 = bucket_base(dym[k]);
            const float b2 = bucket_base(dzm[k]);
            const float bsum = (289.0f * b0 + 17.0f * b1) + b2; // exact small ints
            bf[k] = (float)(int)bsum;
            df[k] = (float)((jblk[k] >> 1) - scan_i);
            mf[k] = 1.0f;
        } else {
            bf[k] = 0.0f; df[k] = 0.0f; mf[k] = 0.0f;
        }
    }

    o_dxyz[0] = make_float4(dxm[0], dym[0], dzm[0], dxm[1]);
    o_dxyz[1] = make_float4(dym[1], dzm[1], dxm[2], dym[2]);
    o_dxyz[2] = make_float4(dzm[2], dxm[3], dym[3], dzm[3]);
    o_bkt[0]  = make_float4(bf[0], bf[1], bf[2], bf[3]);
    o_dsc[0]  = make_float4(df[0], df[1], df[2], df[3]);
    o_msk[0]  = make_float4(mf[0], mf[1], mf[2], mf[3]);
}

extern "C" void kernel_launch(void* const* d_in, const int* in_sizes, int n_in,
                              void* d_out, int out_size, void* d_ws, size_t ws_size,
                              hipStream_t stream) {
    const float* xyz  = (const float*)d_in[0];
    const int*   grid = (const int*)d_in[1];
    float*       out  = (float*)d_out;
    const int N = in_sizes[0] / 3; // xyz is (N,3); N=3072, divisible by 4

    const int BLOCK = 256;               // 256 threads x 4 j = 1024 j per block
    const int jquads = N / 4;
    dim3 gdim((jquads + BLOCK - 1) / BLOCK, N, 1);
    pair_kernel<<<gdim, dim3(BLOCK, 1, 1), 0, stream>>>(xyz, grid, out, N);
}